// Round 5
// baseline (1015.780 us; speedup 1.0000x reference)
//
#include <hip/hip_runtime.h>
#include <cstdint>

#define GR  16     // batches per block
#define KT  2048   // C*D

// W4 quad layout: W4[e4*128 + k*4 + dd] = W[j][k][m], e = j*32+m, e4 = e>>2, dd = e&3
__global__ __launch_bounds__(1024) void wtrans_kernel(const float* __restrict__ W,
                                                      float* __restrict__ W4) {
    int j = blockIdx.x;           // [0,64)
    int t = threadIdx.x;          // k*32 + m
    int k = t >> 5, m = t & 31;
    int e = j * 32 + m;
    W4[(e >> 2) * 128 + k * 4 + (e & 3)] = W[j * 1024 + t];
}

template <int CTRL>
__device__ __forceinline__ float dpp_add(float v) {
    int moved = __builtin_amdgcn_update_dpp(0, __float_as_int(v), CTRL, 0xF, 0xF, true);
    return v + __int_as_float(moved);
}

// 256 threads = 4 waves; wave w owns k-octet [8w, 8w+8); GR=16 batches/block.
// x: global->VGPR streaming (16 quads/j in flight); W: L2-resident scattered reads.
// LDS only for partial/S gather (~18.6 KB) -> 2 blocks/CU at <=256 VGPR.
__global__ __launch_bounds__(256, 2) void ipf_kernel(const float* __restrict__ x,
                                                     const float* __restrict__ W4,
                                                     float* __restrict__ out) {
    __shared__ float Pp[32 * 129];   // rows [w*8+g], 128 payload + 1 pad
    __shared__ float Sl[GR * 32];
    const int t = threadIdx.x;
    const int w = t >> 6;            // k-octet owner
    const int l = t & 63;
    const long long b0 = (long long)blockIdx.x * GR;
    const float* __restrict__ xb = x + b0 * KT;
    const float4* __restrict__ xq = (const float4*)xb;

    float acc[GR][8];
    #pragma unroll
    for (int bb = 0; bb < GR; ++bb)
        #pragma unroll
        for (int kk = 0; kk < 8; ++kk) acc[bb][kk] = 0.0f;

    #pragma unroll
    for (int j = 0; j < 8; ++j) {
        const int e4 = j * 64 + l;
        // x first (HBM latency), 16 coalesced quad loads
        float4 xv[GR];
        #pragma unroll
        for (int bb = 0; bb < GR; ++bb) xv[bb] = xq[bb * 512 + e4];
        // W in two k-quad half-passes (keeps live W regs at 16)
        const float4* wp = (const float4*)(W4 + e4 * 128 + w * 32);
        #pragma unroll
        for (int h = 0; h < 2; ++h) {
            float4 wv[4];
            #pragma unroll
            for (int q = 0; q < 4; ++q) wv[q] = wp[h * 4 + q];
            #pragma unroll
            for (int bb = 0; bb < GR; ++bb) {
                #pragma unroll
                for (int q = 0; q < 4; ++q) {
                    const int kk = h * 4 + q;
                    acc[bb][kk] += xv[bb].x * wv[q].x;
                    acc[bb][kk] += xv[bb].y * wv[q].y;
                    acc[bb][kk] += xv[bb].z * wv[q].z;
                    acc[bb][kk] += xv[bb].w * wv[q].w;
                }
            }
        }
    }

    // intra-wave 8-lane DPP reduction (VALU pipe)
    #pragma unroll
    for (int bb = 0; bb < GR; ++bb)
        #pragma unroll
        for (int kk = 0; kk < 8; ++kk) {
            float v = acc[bb][kk];
            v = dpp_add<0x111>(v);   // row_shr:1
            v = dpp_add<0x112>(v);   // row_shr:2
            v = dpp_add<0x114>(v);   // row_shr:4 -> lane (l&7)==7 holds 8-lane sum
            acc[bb][kk] = v;
        }

    if ((l & 7) == 7) {
        const int g = l >> 3;
        float* row = Pp + (w * 8 + g) * 129;
        #pragma unroll
        for (int bb = 0; bb < GR; ++bb) {
            *(float4*)(row + bb * 8)     = make_float4(acc[bb][0], acc[bb][1], acc[bb][2], acc[bb][3]);
            *(float4*)(row + bb * 8 + 4) = make_float4(acc[bb][4], acc[bb][5], acc[bb][6], acc[bb][7]);
        }
    }
    __syncthreads();

    // gather: S[bb][k] = sum_g Pp[(k>>3)*8+g][bb*8 + (k&7)]; thread covers 2 k's
    {
        const int bb = t >> 4;
        const int kp = (t & 15) * 2;
        #pragma unroll
        for (int u = 0; u < 2; ++u) {
            const int k = kp + u;
            const int wq = k >> 3, kk = k & 7;
            float s = 0.0f;
            #pragma unroll
            for (int g = 0; g < 8; ++g)
                s += Pp[(wq * 8 + g) * 129 + bb * 8 + kk];
            Sl[bb * 32 + k] = s;
        }
    }
    __syncthreads();

    // phase 2: thread covers bb = t>>4, i in {ih, ih+16, ih+32, ih+48}; x re-read L1/L2-hot
    {
        const int bb = t >> 4;
        const int ih = t & 15;
        const float4* sv4 = (const float4*)(Sl + bb * 32);  // broadcast reads
        #pragma unroll
        for (int u = 0; u < 4; ++u) {
            const int i = ih + u * 16;
            const float4* xr = (const float4*)(xb + bb * KT + i * 32);
            float s = 0.0f;
            #pragma unroll
            for (int q = 0; q < 8; ++q) {
                const float4 xv = xr[q];
                const float4 sv = sv4[q];
                s += xv.x * sv.x + xv.y * sv.y + xv.z * sv.z + xv.w * sv.w;
            }
            const float e2 = __expf(2.0f * s);   // tanh(s) = 1 - 2/(e^{2s}+1)
            out[(b0 + bb) * 64 + i] = 1.0f - 2.0f / (e2 + 1.0f);
        }
    }
}

extern "C" void kernel_launch(void* const* d_in, const int* in_sizes, int n_in,
                              void* d_out, int out_size, void* d_ws, size_t ws_size,
                              hipStream_t stream) {
    const float* x = (const float*)d_in[0];   // [65536,64,32] fp32
    const float* W = (const float*)d_in[1];   // [64,32,32] fp32
    float* out = (float*)d_out;               // [65536,64] fp32
    float* W4  = (float*)d_ws;                // 512*128 floats = 256 KB scratch

    wtrans_kernel<<<64, 1024, 0, stream>>>(W, W4);
    ipf_kernel<<<65536 / GR, 256, 0, stream>>>(x, W4, out);
}

// Round 6
// 370.544 us; speedup vs baseline: 2.7413x; 2.7413x over previous
//
#include <hip/hip_runtime.h>
#include <cstdint>

#define GR  8      // batches per block
#define KT  2048   // C*D

// W6 k-major layout: W6[k*2048 + j*256 + l*4 + dd] = W[e=(j*64+l)*4+dd][k]
//   (e = j'*32+m with W[j'][k][m]); a wave's (k,j) read is 64 lanes x 16B consecutive = coalesced 1KB
__global__ __launch_bounds__(1024) void wtrans_kernel(const float* __restrict__ W,
                                                      float* __restrict__ W6) {
    int jp = blockIdx.x;          // j' in [0,64)
    int t = threadIdx.x;          // k*32 + m
    int k = t >> 5, m = t & 31;
    int e = jp * 32 + m;
    int e4 = e >> 2, dd = e & 3;
    int j = e4 >> 6, l = e4 & 63;
    W6[k * 2048 + j * 256 + l * 4 + dd] = W[jp * 1024 + t];
}

template <int CTRL>
__device__ __forceinline__ float dpp_add(float v) {
    int moved = __builtin_amdgcn_update_dpp(0, __float_as_int(v), CTRL, 0xF, 0xF, true);
    return v + __int_as_float(moved);
}

// 256 threads = 4 waves; wave w owns k-octet [8w,8w+8); GR=8 batches/block (8192 blocks).
// x: global->VGPR coalesced streaming; W: L2-resident, coalesced via W6.
// ~150 VGPR -> 3 waves/SIMD. LDS only for partial/S gather.
__global__ __launch_bounds__(256, 1) void ipf_kernel(const float* __restrict__ x,
                                                     const float* __restrict__ W6,
                                                     float* __restrict__ out) {
    __shared__ float Pp[32 * 65];    // rows [w*8+g], 64 payload + 1 pad
    __shared__ float Sl[GR * 32];
    const int t = threadIdx.x;
    const int w = t >> 6;            // k-octet owner
    const int l = t & 63;
    const long long b0 = (long long)blockIdx.x * GR;
    const float* __restrict__ xb = x + b0 * KT;
    const float4* __restrict__ xq = (const float4*)xb;

    float acc[GR][8];
    #pragma unroll
    for (int bb = 0; bb < GR; ++bb)
        #pragma unroll
        for (int q = 0; q < 8; ++q) acc[bb][q] = 0.0f;

    #pragma unroll
    for (int j = 0; j < 8; ++j) {
        const int e4 = j * 64 + l;
        // batch-issue all 16 loads of this j-slice (8 x-quads HBM + 8 W-quads L2)
        float4 xv[GR];
        #pragma unroll
        for (int bb = 0; bb < GR; ++bb) xv[bb] = xq[bb * 512 + e4];
        float4 wv[8];
        #pragma unroll
        for (int q = 0; q < 8; ++q)
            wv[q] = ((const float4*)(W6 + (w * 8 + q) * 2048 + j * 256))[l];  // coalesced
        #pragma unroll
        for (int bb = 0; bb < GR; ++bb) {
            #pragma unroll
            for (int q = 0; q < 8; ++q) {
                acc[bb][q] += xv[bb].x * wv[q].x;
                acc[bb][q] += xv[bb].y * wv[q].y;
                acc[bb][q] += xv[bb].z * wv[q].z;
                acc[bb][q] += xv[bb].w * wv[q].w;
            }
        }
    }

    // intra-wave 8-lane DPP reduction (VALU pipe)
    #pragma unroll
    for (int bb = 0; bb < GR; ++bb)
        #pragma unroll
        for (int q = 0; q < 8; ++q) {
            float v = acc[bb][q];
            v = dpp_add<0x111>(v);   // row_shr:1
            v = dpp_add<0x112>(v);   // row_shr:2
            v = dpp_add<0x114>(v);   // row_shr:4 -> lane (l&7)==7 holds 8-lane sum
            acc[bb][q] = v;
        }

    if ((l & 7) == 7) {
        const int g = l >> 3;
        float* row = Pp + (w * 8 + g) * 65;
        #pragma unroll
        for (int bb = 0; bb < GR; ++bb) {
            *(float4*)(row + bb * 8)     = make_float4(acc[bb][0], acc[bb][1], acc[bb][2], acc[bb][3]);
            *(float4*)(row + bb * 8 + 4) = make_float4(acc[bb][4], acc[bb][5], acc[bb][6], acc[bb][7]);
        }
    }
    __syncthreads();

    // gather: S[bb][k] = sum_g Pp[(k>>3)*8+g][bb*8 + (k&7)]; 256 threads = 8bb x 32k
    {
        const int bb = t >> 5, k = t & 31;
        const int wq = k >> 3, kk = k & 7;
        float s = 0.0f;
        #pragma unroll
        for (int g = 0; g < 8; ++g)
            s += Pp[(wq * 8 + g) * 65 + bb * 8 + kk];
        Sl[bb * 32 + k] = s;
    }
    __syncthreads();

    // phase 2: thread covers bb = t>>5, i in {ih, ih+32}; x re-read (L2-hot)
    {
        const int bb = t >> 5;
        const int ih = t & 31;
        const float4* sv4 = (const float4*)(Sl + bb * 32);  // half-wave-uniform broadcast
        #pragma unroll
        for (int u = 0; u < 2; ++u) {
            const int i = ih + u * 32;
            const float4* xr = (const float4*)(xb + bb * KT + i * 32);
            float s = 0.0f;
            #pragma unroll
            for (int q = 0; q < 8; ++q) {
                const float4 xv = xr[q];
                const float4 sv = sv4[q];
                s += xv.x * sv.x + xv.y * sv.y + xv.z * sv.z + xv.w * sv.w;
            }
            const float e2 = __expf(2.0f * s);   // tanh(s) = 1 - 2/(e^{2s}+1)
            out[(b0 + bb) * 64 + i] = 1.0f - 2.0f / (e2 + 1.0f);
        }
    }
}

extern "C" void kernel_launch(void* const* d_in, const int* in_sizes, int n_in,
                              void* d_out, int out_size, void* d_ws, size_t ws_size,
                              hipStream_t stream) {
    const float* x = (const float*)d_in[0];   // [65536,64,32] fp32
    const float* W = (const float*)d_in[1];   // [64,32,32] fp32
    float* out = (float*)d_out;               // [65536,64] fp32
    float* W6  = (float*)d_ws;                // 65536 floats = 256 KB scratch

    wtrans_kernel<<<64, 1024, 0, stream>>>(W, W6);
    ipf_kernel<<<65536 / GR, 256, 0, stream>>>(x, W6, out);
}

// Round 7
// 319.897 us; speedup vs baseline: 3.1753x; 1.1583x over previous
//
#include <hip/hip_runtime.h>
#include <cstdint>

#define GR 8       // batches per block
#define KT 2048    // C*D

typedef const __attribute__((address_space(1))) uint32_t gu32;
typedef __attribute__((address_space(3))) uint32_t lu32;

// W6 k-major layout: W6[k*2048 + j*256 + l*4 + dd] = W[jp][k][m], e=jp*32+m=(j*64+l)*4+dd
// -> a wave's (k,j) read is 64 lanes x 16B consecutive = coalesced 1KB
__global__ __launch_bounds__(1024) void wtrans_kernel(const float* __restrict__ W,
                                                      float* __restrict__ W6) {
    int jp = blockIdx.x;          // [0,64)
    int t = threadIdx.x;          // k*32 + m
    int k = t >> 5, m = t & 31;
    int e = jp * 32 + m;
    int e4 = e >> 2, dd = e & 3;
    int j = e4 >> 6, l = e4 & 63;
    W6[k * 2048 + j * 256 + l * 4 + dd] = W[jp * 1024 + t];
}

template <int CTRL>
__device__ __forceinline__ float dpp_add(float v) {
    int moved = __builtin_amdgcn_update_dpp(0, __float_as_int(v), CTRL, 0xF, 0xF, true);
    return v + __int_as_float(moved);
}

// 512 threads = 8 waves. Wave w owns k-quad [4w,4w+4), stages batch bb=w, phase-2 batch w.
// x: global->LDS in 4 pipelined 16KB chunks (2 j-slices each). W: L2-hot coalesced.
// LDS 74.2KB -> 2 blocks/CU (16 waves). No global x re-read in phase 2.
__global__ __launch_bounds__(512, 2) void ipf_kernel(const float* __restrict__ x,
                                                     const float* __restrict__ W6,
                                                     float* __restrict__ out) {
    __shared__ float xs[GR * KT];     // 64 KB: xs[bb][2048]
    __shared__ float Pp[64 * 36];     // 9.2 KB: 64 partial rows, stride 36 (16B-aligned, bank-spread)
    __shared__ float Sl[GR * 32];     // 1 KB
    const int t = threadIdx.x;
    const int w = t >> 6;             // wave id
    const int l = t & 63;
    const long long b0 = (long long)blockIdx.x * GR;
    const float* __restrict__ xb = x + b0 * KT;

    // ---- stage chunk c (j-slices 2c, 2c+1): wave w stages its batch's 2KB, linear dest ----
    #define STAGE(c)                                                                          \
        {                                                                                     \
            const char* gsrc = (const char*)(xb + w * KT + (c) * 512);                        \
            char* ldst = (char*)(xs + w * KT + (c) * 512);                                    \
            __builtin_amdgcn_global_load_lds((gu32*)(gsrc + l * 16), (lu32*)ldst, 16, 0, 0);  \
            __builtin_amdgcn_global_load_lds((gu32*)(gsrc + 1024 + l * 16),                   \
                                             (lu32*)(ldst + 1024), 16, 0, 0);                 \
        }

    STAGE(0);
    __syncthreads();   // chunk 0 resident

    float acc[GR][4];
    #pragma unroll
    for (int bb = 0; bb < GR; ++bb)
        #pragma unroll
        for (int q = 0; q < 4; ++q) acc[bb][q] = 0.0f;

    #pragma unroll
    for (int c = 0; c < 4; ++c) {
        if (c < 3) STAGE(c + 1);      // issue next chunk BEFORE compute (overlaps)
        #pragma unroll
        for (int u = 0; u < 2; ++u) {
            const int j = 2 * c + u;
            float4 wv[4];
            #pragma unroll
            for (int q = 0; q < 4; ++q)
                wv[q] = ((const float4*)(W6 + (w * 4 + q) * 2048 + j * 256))[l];  // coalesced 1KB
            float4 xv[GR];
            #pragma unroll
            for (int bb = 0; bb < GR; ++bb)
                xv[bb] = ((const float4*)(xs + bb * KT + j * 256))[l];            // ds_read_b128, conflict-free
            #pragma unroll
            for (int bb = 0; bb < GR; ++bb)
                #pragma unroll
                for (int q = 0; q < 4; ++q) {
                    acc[bb][q] += xv[bb].x * wv[q].x;
                    acc[bb][q] += xv[bb].y * wv[q].y;
                    acc[bb][q] += xv[bb].z * wv[q].z;
                    acc[bb][q] += xv[bb].w * wv[q].w;
                }
        }
        __syncthreads();  // drains stage(c+1) (vmcnt 0) -> chunk c+1 resident next iter
    }

    // ---- intra-wave 8-lane DPP reduction (VALU pipe) ----
    #pragma unroll
    for (int bb = 0; bb < GR; ++bb)
        #pragma unroll
        for (int q = 0; q < 4; ++q) {
            float v = acc[bb][q];
            v = dpp_add<0x111>(v);    // row_shr:1
            v = dpp_add<0x112>(v);    // row_shr:2
            v = dpp_add<0x114>(v);    // row_shr:4 -> lane (l&7)==7 holds 8-lane sum
            acc[bb][q] = v;
        }

    if ((l & 7) == 7) {
        const int g = l >> 3;
        float* row = Pp + (w * 8 + g) * 36;
        #pragma unroll
        for (int bb = 0; bb < GR; ++bb)
            *(float4*)(row + bb * 4) = make_float4(acc[bb][0], acc[bb][1], acc[bb][2], acc[bb][3]);
    }
    __syncthreads();

    // ---- gather: S[bb][k] = sum_g Pp[(k>>2)*8+g][bb*4+(k&3)]; threads t<256 = 8bb x 32k ----
    if (t < 256) {
        const int bb = t >> 5, k = t & 31;
        const int wq = k >> 2, kk = k & 3;
        float s = 0.0f;
        #pragma unroll
        for (int g = 0; g < 8; ++g)
            s += Pp[(wq * 8 + g) * 36 + bb * 4 + kk];
        Sl[bb * 32 + k] = s;
    }
    __syncthreads();

    // ---- phase 2: out[b0+w, l] = tanh(sum_d x[w][l*32+d] * S[w][d]), x from LDS ----
    {
        float s = 0.0f;
        #pragma unroll
        for (int d = 0; d < 32; ++d) {
            const int dd = (d + l) & 31;   // per-lane rotation: bank=(d+l)&31, conflict-free b32
            s += xs[w * KT + l * 32 + dd] * Sl[w * 32 + dd];
        }
        const float e2 = __expf(2.0f * s); // tanh(s) = 1 - 2/(e^{2s}+1)
        out[(b0 + w) * 64 + l] = 1.0f - 2.0f / (e2 + 1.0f);
    }
    #undef STAGE
}

extern "C" void kernel_launch(void* const* d_in, const int* in_sizes, int n_in,
                              void* d_out, int out_size, void* d_ws, size_t ws_size,
                              hipStream_t stream) {
    const float* x = (const float*)d_in[0];   // [65536,64,32] fp32
    const float* W = (const float*)d_in[1];   // [64,32,32] fp32
    float* out = (float*)d_out;               // [65536,64] fp32
    float* W6  = (float*)d_ws;                // 65536 floats = 256 KB scratch

    wtrans_kernel<<<64, 1024, 0, stream>>>(W, W6);
    ipf_kernel<<<65536 / GR, 512, 0, stream>>>(x, W6, out);
}

// Round 8
// 262.286 us; speedup vs baseline: 3.8728x; 1.2196x over previous
//
#include <hip/hip_runtime.h>
#include <cstdint>

#define KT     2048              // C*D
#define GR     4                 // batches per tile
#define NBLK   512               // persistent blocks
#define BPB    (65536 / NBLK)    // 128 batches per block
#define NTILES (BPB / GR)        // 32 tiles per block

typedef const __attribute__((address_space(1))) uint32_t gu32;
typedef __attribute__((address_space(3))) uint32_t lu32;

// W6 k-major: W6[k*2048 + j*256 + l*4 + dd] = W[jp][k][m], e = jp*32+m = (j*64+l)*4+dd
// -> any (k,j) wave read is 64 lanes x 16B consecutive = coalesced 1KB
__global__ __launch_bounds__(1024) void wtrans_kernel(const float* __restrict__ W,
                                                      float* __restrict__ W6) {
    int jp = blockIdx.x;          // [0,64)
    int t = threadIdx.x;          // k*32 + m
    int k = t >> 5, m = t & 31;
    int e = jp * 32 + m;
    int e4 = e >> 2, dd = e & 3;
    int j = e4 >> 6, l = e4 & 63;
    W6[k * 2048 + j * 256 + l * 4 + dd] = W[jp * 1024 + t];
}

template <int CTRL>
__device__ __forceinline__ float dpp_add(float v) {
    int moved = __builtin_amdgcn_update_dpp(0, __float_as_int(v), CTRL, 0xF, 0xF, true);
    return v + __int_as_float(moved);
}

// 512 threads = 8 waves = (jh in 2 j-halves) x (w2 in 4 k-octets).
// W slice lives in 128 VGPRs per thread, loaded ONCE per block.
// x double-buffered in LDS, staged one tile ahead (global_load_lds w16).
__global__ __launch_bounds__(512, 2) void ipf_kernel(const float* __restrict__ x,
                                                     const float* __restrict__ W6,
                                                     float* __restrict__ out) {
    __shared__ float xs[2][GR * KT];   // 2 x 32 KB
    __shared__ float Pp[64 * 33];      // 8.25 KB partials: row (w*8+g), 32 payload + 1 pad
    __shared__ float Sl[GR * 32];      // 512 B
    const int t = threadIdx.x;
    const int w = t >> 6, l = t & 63;
    const int jh = w >> 2;             // j-half: j in [jh*4, jh*4+4)
    const int w2 = w & 3;              // k-octet: k in [w2*8, w2*8+8)
    const long long bbase = (long long)blockIdx.x * BPB;

    // stage tile tt (GR*8KB = 32 chunks of 1KB) into buffer bf; wave issues 4
    #define STAGE(tt, bf)                                                                     \
        {                                                                                     \
            const char* gs = (const char*)(x + (bbase + (long long)(tt) * GR) * KT);          \
            char* ld = (char*)xs[bf];                                                         \
            _Pragma("unroll")                                                                 \
            for (int u = 0; u < 4; ++u) {                                                     \
                const int s = w * 4 + u;                                                      \
                __builtin_amdgcn_global_load_lds((gu32*)(gs + s * 1024 + l * 16),             \
                                                 (lu32*)(ld + s * 1024), 16, 0, 0);           \
            }                                                                                 \
        }

    STAGE(0, 0);                       // x pipeline starts first

    // ---- W slice -> registers (once): Wr[q][jj] for k = w2*8+q, j = jh*4+jj ----
    float4 Wr[8][4];
    #pragma unroll
    for (int q = 0; q < 8; ++q)
        #pragma unroll
        for (int jj = 0; jj < 4; ++jj)
            Wr[q][jj] = *(const float4*)(W6 + (w2 * 8 + q) * 2048 + (jh * 4 + jj) * 256 + l * 4);

    int cur = 0;
    for (int tt = 0; tt < NTILES; ++tt) {
        __syncthreads();               // buf[cur] resident; prev phase-2 done with buf[cur]
        if (tt + 1 < NTILES) STAGE(tt + 1, cur ^ 1);   // issue next tile BEFORE compute

        // ---- compute: acc[bb][q] = sum over this wave's j-half ----
        float acc[GR][8];
        #pragma unroll
        for (int bb = 0; bb < GR; ++bb)
            #pragma unroll
            for (int q = 0; q < 8; ++q) acc[bb][q] = 0.0f;

        const float* xc = xs[cur];
        #pragma unroll
        for (int jj = 0; jj < 4; ++jj) {
            const int j = jh * 4 + jj;
            float4 xv[GR];
            #pragma unroll
            for (int bb = 0; bb < GR; ++bb)
                xv[bb] = *(const float4*)(xc + bb * KT + j * 256 + l * 4);  // conflict-free b128
            #pragma unroll
            for (int bb = 0; bb < GR; ++bb)
                #pragma unroll
                for (int q = 0; q < 8; ++q) {
                    acc[bb][q] += xv[bb].x * Wr[q][jj].x;
                    acc[bb][q] += xv[bb].y * Wr[q][jj].y;
                    acc[bb][q] += xv[bb].z * Wr[q][jj].z;
                    acc[bb][q] += xv[bb].w * Wr[q][jj].w;
                }
        }

        // ---- 8-lane DPP reduce (VALU pipe) ----
        #pragma unroll
        for (int bb = 0; bb < GR; ++bb)
            #pragma unroll
            for (int q = 0; q < 8; ++q) {
                float v = acc[bb][q];
                v = dpp_add<0x111>(v);    // row_shr:1
                v = dpp_add<0x112>(v);    // row_shr:2
                v = dpp_add<0x114>(v);    // row_shr:4 -> lane (l&7)==7 holds 8-lane sum
                acc[bb][q] = v;
            }

        if ((l & 7) == 7) {
            const int g = l >> 3;
            float* row = Pp + (w * 8 + g) * 33;
            #pragma unroll
            for (int bb = 0; bb < GR; ++bb) {
                *(float4*)(row + bb * 8)     = make_float4(acc[bb][0], acc[bb][1], acc[bb][2], acc[bb][3]);
                *(float4*)(row + bb * 8 + 4) = make_float4(acc[bb][4], acc[bb][5], acc[bb][6], acc[bb][7]);
            }
        }
        __syncthreads();

        // ---- gather: S[bb][k] = sum over jh2(2) x g(8) ----
        if (t < 128) {
            const int bb = t >> 5, k = t & 31;
            const int kq = k >> 3, kk = k & 7;
            float s = 0.0f;
            #pragma unroll
            for (int jh2 = 0; jh2 < 2; ++jh2)
                #pragma unroll
                for (int g = 0; g < 8; ++g)
                    s += Pp[((jh2 * 4 + kq) * 8 + g) * 33 + bb * 8 + kk];
            Sl[bb * 32 + k] = s;
        }
        __syncthreads();

        // ---- phase 2: out[bb, i] = tanh(dot(x[bb][i*32..], S[bb])) ----
        if (t < 256) {
            const int bb = t >> 6, i = t & 63;
            const float* xr = xc + bb * KT + i * 32;
            const float* sr = Sl + bb * 32;
            float s = 0.0f;
            #pragma unroll
            for (int d = 0; d < 32; ++d) {
                const int dd = (d + i) & 31;   // rotation: 2 lanes/bank = free
                s += xr[dd] * sr[dd];
            }
            const float e2 = __expf(2.0f * s);  // tanh(s) = 1 - 2/(e^{2s}+1)
            out[(bbase + (long long)tt * GR + bb) * 64 + i] = 1.0f - 2.0f / (e2 + 1.0f);
        }
        cur ^= 1;
    }
    #undef STAGE
}

extern "C" void kernel_launch(void* const* d_in, const int* in_sizes, int n_in,
                              void* d_out, int out_size, void* d_ws, size_t ws_size,
                              hipStream_t stream) {
    const float* x = (const float*)d_in[0];   // [65536,64,32] fp32
    const float* W = (const float*)d_in[1];   // [64,32,32] fp32
    float* out = (float*)d_out;               // [65536,64] fp32
    float* W6  = (float*)d_ws;                // 65536 floats = 256 KB scratch

    wtrans_kernel<<<64, 1024, 0, stream>>>(W, W6);
    ipf_kernel<<<NBLK, 512, 0, stream>>>(x, W6, out);
}